// Round 1
// baseline (70.549 us; speedup 1.0000x reference)
//
#include <hip/hip_runtime.h>

// 5-level db4-style wavedec, pywt 'symmetric' extension.
// Lengths: 8192 -> 4099 -> 2053 -> 1030 -> 518 -> 262
// Output layout (flat, per return order): approx(262), d5(262), d4(518),
// d3(1030), d2(2053), d1(4099) -- each (4096 rows x len).

static constexpr int ROWS = 64 * 64;     // 4096
static constexpr int N0 = 8192;
static constexpr int LEN1 = 4099, LEN2 = 2053, LEN3 = 1030, LEN4 = 518, LEN5 = 262;

__global__ __launch_bounds__(256)
void wavedec5_kernel(const float* __restrict__ x,
                     const float* __restrict__ dlo,
                     const float* __restrict__ dhi,
                     float* __restrict__ out)
{
    __shared__ __align__(16) float bufA[N0];      // 32 KB
    __shared__ __align__(16) float bufB[LEN1 + 1]; // 16.4 KB

    const int row = blockIdx.x;
    const int tid = threadIdx.x;

    // filters (broadcast loads, L1/L2-cached)
    float h[8], g[8];
#pragma unroll
    for (int i = 0; i < 8; ++i) { h[i] = dlo[i]; g[i] = dhi[i]; }

    // stage the row into LDS, float4-coalesced: 2048 float4, 8 per thread
    {
        const float4* __restrict__ xin =
            reinterpret_cast<const float4*>(x) + (size_t)row * (N0 / 4);
        float4* bA4 = reinterpret_cast<float4*>(bufA);
#pragma unroll
        for (int i = 0; i < (N0 / 4) / 256; ++i)
            bA4[tid + i * 256] = xin[tid + i * 256];
    }
    __syncthreads();

    const int lens[6] = {N0, LEN1, LEN2, LEN3, LEN4, LEN5};
    const size_t detoff[5] = {16896000u,   // d1
                              8486912u,    // d2
                              4268032u,    // d3
                              2146304u,    // d4
                              1073152u};   // d5
    float* __restrict__ aout = out + (size_t)row * LEN5;  // approx

    float* src = bufA;
    float* dst = bufB;

#pragma unroll
    for (int lvl = 0; lvl < 5; ++lvl) {
        const int n = lens[lvl];
        const int m = lens[lvl + 1];
        float* __restrict__ dout = out + detoff[lvl] + (size_t)row * m;
        for (int pos = tid; pos < m; pos += 256) {
            const int s0 = 2 * pos + 1;
            float a = 0.f, d = 0.f;
#pragma unroll
            for (int q = 0; q < 8; ++q) {
                int s = s0 - q;
                // half-sample symmetric reflection (pad width 7 << n, single bounce)
                int idx = (s < 0) ? (-1 - s) : ((s >= n) ? (2 * n - 1 - s) : s);
                const float v = src[idx];
                a = fmaf(h[q], v, a);
                d = fmaf(g[q], v, d);
            }
            dout[pos] = d;
            if (lvl == 4) aout[pos] = a;   // final approx straight to global
            else         dst[pos]  = a;
        }
        __syncthreads();
        float* t = src; src = dst; dst = t;
    }
}

extern "C" void kernel_launch(void* const* d_in, const int* in_sizes, int n_in,
                              void* d_out, int out_size, void* d_ws, size_t ws_size,
                              hipStream_t stream) {
    const float* x   = (const float*)d_in[0];
    const float* dlo = (const float*)d_in[1];
    const float* dhi = (const float*)d_in[2];
    float* out = (float*)d_out;
    wavedec5_kernel<<<ROWS, 256, 0, stream>>>(x, dlo, dhi, out);
}

// Round 2
// 62.249 us; speedup vs baseline: 1.1333x; 1.1333x over previous
//
#include <hip/hip_runtime.h>

// 5-level wavedec (filter len 8, pywt 'symmetric'), B*C=4096 rows of 8192 f32.
// Lengths: 8192 -> 4099 -> 2053 -> 1030 -> 518 -> 262
// Out layout: approx(262) @0, d5(262), d4(518), d3(1030), d2(2053), d1(4099).

static constexpr int ROWS = 4096;
static constexpr int N0 = 8192;
static constexpr int L1n = 4099, L2n = 2053, L3n = 1030, L4n = 518, L5n = 262;
static constexpr size_t OFF_D5 = 1073152u;
static constexpr size_t OFF_D4 = 2146304u;
static constexpr size_t OFF_D3 = 4268032u;
static constexpr size_t OFF_D2 = 8486912u;
static constexpr size_t OFF_D1 = 16896000u;

// One DWT level: src (LDS or global), n input len, m output len.
// Interior positions use 4x float2 vector reads (no index math, no conflicts);
// only ~6 edge positions per level take the branchy reflect path.
__device__ __forceinline__ void dwt_level(
    const float* __restrict__ src, int n, int m,
    const float* __restrict__ h, const float* __restrict__ g,
    float* __restrict__ adst, float* __restrict__ ddst, int tid)
{
    for (int pos = tid; pos < m; pos += 256) {
        float a = 0.f, d = 0.f;
        if (pos >= 3 && 2 * pos + 1 < n) {
            // window v[j] = src[2p-6+j], j=0..7 ; tap q uses v[7-q]
            const float2* s2 = reinterpret_cast<const float2*>(src) + (pos - 3);
            float2 w0 = s2[0], w1 = s2[1], w2 = s2[2], w3 = s2[3];
            a = fmaf(h[7], w0.x, a); d = fmaf(g[7], w0.x, d);
            a = fmaf(h[6], w0.y, a); d = fmaf(g[6], w0.y, d);
            a = fmaf(h[5], w1.x, a); d = fmaf(g[5], w1.x, d);
            a = fmaf(h[4], w1.y, a); d = fmaf(g[4], w1.y, d);
            a = fmaf(h[3], w2.x, a); d = fmaf(g[3], w2.x, d);
            a = fmaf(h[2], w2.y, a); d = fmaf(g[2], w2.y, d);
            a = fmaf(h[1], w3.x, a); d = fmaf(g[1], w3.x, d);
            a = fmaf(h[0], w3.y, a); d = fmaf(g[0], w3.y, d);
        } else {
            const int s0 = 2 * pos + 1;
#pragma unroll
            for (int q = 0; q < 8; ++q) {
                int s = s0 - q;
                int idx = (s < 0) ? (-1 - s) : ((s >= n) ? (2 * n - 1 - s) : s);
                const float v = src[idx];
                a = fmaf(h[q], v, a);
                d = fmaf(g[q], v, d);
            }
        }
        ddst[pos] = d;
        adst[pos] = a;
    }
}

__global__ __launch_bounds__(256, 6)
void wavedec5_kernel(const float* __restrict__ x,
                     const float* __restrict__ dlo,
                     const float* __restrict__ dhi,
                     float* __restrict__ out)
{
    // ping-pong inside one small buffer: [0..4098] <-> [4100..6152]
    __shared__ __align__(16) float lds[L1n + 1 + L2n];  // 6153 f32 = 24.6 KB

    const int row = blockIdx.x;
    const int tid = threadIdx.x;

    float h[8], g[8];
#pragma unroll
    for (int i = 0; i < 8; ++i) { h[i] = dlo[i]; g[i] = dhi[i]; }

    const float* __restrict__ xr = x + (size_t)row * N0;

    // L1: global -> (approx1 in lds[0..4098], d1 -> global). Window reads are
    // coalesced 512B float2 vector loads with heavy L1 line reuse.
    dwt_level(xr, N0, L1n, h, g, lds, out + OFF_D1 + (size_t)row * L1n, tid);
    __syncthreads();
    // L2: lds[0..4098] -> lds[4100..6152], d2 -> global
    dwt_level(lds, L1n, L2n, h, g, lds + 4100, out + OFF_D2 + (size_t)row * L2n, tid);
    __syncthreads();
    // L3: lds[4100..6152] -> lds[0..1029], d3 -> global
    dwt_level(lds + 4100, L2n, L3n, h, g, lds, out + OFF_D3 + (size_t)row * L3n, tid);
    __syncthreads();
    // L4: lds[0..1029] -> lds[4100..4617], d4 -> global
    dwt_level(lds, L3n, L4n, h, g, lds + 4100, out + OFF_D4 + (size_t)row * L4n, tid);
    __syncthreads();
    // L5: lds[4100..4617] -> approx & d5 straight to global
    dwt_level(lds + 4100, L4n, L5n, h, g,
              out + (size_t)row * L5n, out + OFF_D5 + (size_t)row * L5n, tid);
}

extern "C" void kernel_launch(void* const* d_in, const int* in_sizes, int n_in,
                              void* d_out, int out_size, void* d_ws, size_t ws_size,
                              hipStream_t stream) {
    const float* x   = (const float*)d_in[0];
    const float* dlo = (const float*)d_in[1];
    const float* dhi = (const float*)d_in[2];
    float* out = (float*)d_out;
    wavedec5_kernel<<<ROWS, 256, 0, stream>>>(x, dlo, dhi, out);
}

// Round 3
// 59.110 us; speedup vs baseline: 1.1935x; 1.0531x over previous
//
#include <hip/hip_runtime.h>

// 5-level wavedec (filter len 8, pywt 'symmetric'), B*C=4096 rows of 8192 f32.
// Lengths: 8192 -> 4099 -> 2053 -> 1030 -> 518 -> 262
// Out layout: approx(262) @0, d5(262), d4(518), d3(1030), d2(2053), d1(4099).
// Each thread computes 4 consecutive outputs from one 16-float window:
// 8x float2 loads -> 64 FMA -> 8 stores. 4x fewer mem instrs per output.

static constexpr int ROWS = 4096;
static constexpr int N0 = 8192;
static constexpr int L1n = 4099, L2n = 2053, L3n = 1030, L4n = 518, L5n = 262;
static constexpr size_t OFF_D5 = 1073152u;
static constexpr size_t OFF_D4 = 2146304u;
static constexpr size_t OFF_D3 = 4268032u;
static constexpr size_t OFF_D2 = 8486912u;
static constexpr size_t OFF_D1 = 16896000u;

__device__ __forceinline__ void dwt_level4(
    const float* __restrict__ src, int n, int m,
    const float* __restrict__ h, const float* __restrict__ g,
    float* __restrict__ adst, float* __restrict__ ddst, int tid)
{
    const int ngroups = (m + 3) >> 2;
    const int jin_max = (n - 10) >> 3;   // group j interior iff 1 <= j <= jin_max
    for (int j = tid; j < ngroups; j += 256) {
        const int p0 = 4 * j;
        if (j >= 1 && j <= jin_max && p0 + 3 < m) {
            // w[0..15] = src[8j-6 .. 8j+9]  (float2-aligned: 8j-6 is even)
            const float2* __restrict__ s2 =
                reinterpret_cast<const float2*>(src + (8 * j - 6));
            float w[16];
#pragma unroll
            for (int t = 0; t < 8; ++t) {
                const float2 v = s2[t];
                w[2 * t] = v.x; w[2 * t + 1] = v.y;
            }
#pragma unroll
            for (int r = 0; r < 4; ++r) {
                float aa = 0.f, dd = 0.f;
#pragma unroll
                for (int q = 0; q < 8; ++q) {
                    const float v = w[2 * r + 7 - q];   // src[2(p0+r)+1-q]
                    aa = fmaf(h[q], v, aa);
                    dd = fmaf(g[q], v, dd);
                }
                ddst[p0 + r] = dd;
                adst[p0 + r] = aa;
            }
        } else {
            // edge groups: branchy symmetric-reflect path (few per level)
#pragma unroll 4
            for (int r = 0; r < 4; ++r) {
                const int pos = p0 + r;
                if (pos >= m) break;
                const int s0 = 2 * pos + 1;
                float aa = 0.f, dd = 0.f;
#pragma unroll
                for (int q = 0; q < 8; ++q) {
                    int s = s0 - q;
                    int idx = (s < 0) ? (-1 - s) : ((s >= n) ? (2 * n - 1 - s) : s);
                    const float v = src[idx];
                    aa = fmaf(h[q], v, aa);
                    dd = fmaf(g[q], v, dd);
                }
                ddst[pos] = dd;
                adst[pos] = aa;
            }
        }
    }
}

__global__ __launch_bounds__(256, 6)
void wavedec5_kernel(const float* __restrict__ x,
                     const float* __restrict__ dlo,
                     const float* __restrict__ dhi,
                     float* __restrict__ out)
{
    // ping-pong inside one small buffer: [0..4098] <-> [4100..6152]
    __shared__ __align__(16) float lds[L1n + 1 + L2n];  // 6153 f32 = 24.6 KB

    const int row = blockIdx.x;
    const int tid = threadIdx.x;

    float h[8], g[8];
#pragma unroll
    for (int i = 0; i < 8; ++i) { h[i] = dlo[i]; g[i] = dhi[i]; }

    const float* __restrict__ xr = x + (size_t)row * N0;

    // L1: global -> (approx1 in lds[0..4098], d1 -> global)
    dwt_level4(xr, N0, L1n, h, g, lds, out + OFF_D1 + (size_t)row * L1n, tid);
    __syncthreads();
    // L2: lds[0..4098] -> lds[4100..6152], d2 -> global
    dwt_level4(lds, L1n, L2n, h, g, lds + 4100, out + OFF_D2 + (size_t)row * L2n, tid);
    __syncthreads();
    // L3: lds[4100..6152] -> lds[0..1029], d3 -> global
    dwt_level4(lds + 4100, L2n, L3n, h, g, lds, out + OFF_D3 + (size_t)row * L3n, tid);
    __syncthreads();
    // L4: lds[0..1029] -> lds[4100..4617], d4 -> global
    dwt_level4(lds, L3n, L4n, h, g, lds + 4100, out + OFF_D4 + (size_t)row * L4n, tid);
    __syncthreads();
    // L5: lds[4100..4617] -> approx & d5 straight to global
    dwt_level4(lds + 4100, L4n, L5n, h, g,
               out + (size_t)row * L5n, out + OFF_D5 + (size_t)row * L5n, tid);
}

extern "C" void kernel_launch(void* const* d_in, const int* in_sizes, int n_in,
                              void* d_out, int out_size, void* d_ws, size_t ws_size,
                              hipStream_t stream) {
    const float* x   = (const float*)d_in[0];
    const float* dlo = (const float*)d_in[1];
    const float* dhi = (const float*)d_in[2];
    float* out = (float*)d_out;
    wavedec5_kernel<<<ROWS, 256, 0, stream>>>(x, dlo, dhi, out);
}